// Round 17
// baseline (103.767 us; speedup 1.0000x reference)
//
#include <hip/hip_runtime.h>
#include <hip/hip_bf16.h>

#define B_ROWS 4096
#define NROWS  8192   // 2B
#define D      256
#define TT     264    // tiles per strip-pair (32-col tiles)
#define NBLK2  512    // 16 pairs * 32 segments

typedef __attribute__((ext_vector_type(8))) short bf16x8;
typedef __attribute__((ext_vector_type(4))) float floatx4;

// ---------------------------------------------------------------------------
// Kernel 1: fused normalize + pos + selfdot + zero-init rowsum/out/counter.
// ---------------------------------------------------------------------------
__global__ __launch_bounds__(256) void norm_pos_kernel(
    const float* __restrict__ xi, const float* __restrict__ xj,
    short* __restrict__ z, float* __restrict__ pos,
    float* __restrict__ selfdot, float* __restrict__ rowsum,
    float* __restrict__ out, unsigned int* __restrict__ counter) {
    int gt = blockIdx.x * 256 + threadIdx.x;
    if (gt < NROWS) rowsum[gt] = 0.f;
    if (gt == 0) { out[0] = 0.f; counter[0] = 0u; }

    int p    = blockIdx.x * 4 + (threadIdx.x >> 6);
    int lane = threadIdx.x & 63;
    float4 v1 = ((const float4*)(xi + (size_t)p * D))[lane];
    float4 v2 = ((const float4*)(xj + (size_t)p * D))[lane];
    float ss1 = v1.x * v1.x + v1.y * v1.y + v1.z * v1.z + v1.w * v1.w;
    float ss2 = v2.x * v2.x + v2.y * v2.y + v2.z * v2.z + v2.w * v2.w;
#pragma unroll
    for (int off = 32; off > 0; off >>= 1) {
        ss1 += __shfl_xor(ss1, off);
        ss2 += __shfl_xor(ss2, off);
    }
    float sc1 = 1.0f / fmaxf(sqrtf(ss1), 1e-12f);
    float sc2 = 1.0f / fmaxf(sqrtf(ss2), 1e-12f);

    union { __hip_bfloat16 h[4]; short4 s4; } u1, u2;
    u1.h[0] = __float2bfloat16(v1.x * sc1); u1.h[1] = __float2bfloat16(v1.y * sc1);
    u1.h[2] = __float2bfloat16(v1.z * sc1); u1.h[3] = __float2bfloat16(v1.w * sc1);
    u2.h[0] = __float2bfloat16(v2.x * sc2); u2.h[1] = __float2bfloat16(v2.y * sc2);
    u2.h[2] = __float2bfloat16(v2.z * sc2); u2.h[3] = __float2bfloat16(v2.w * sc2);
    ((short4*)(z + (size_t)p * D))[lane]            = u1.s4;
    ((short4*)(z + (size_t)(p + B_ROWS) * D))[lane] = u2.s4;

    float sd1 = 0.f, sd2 = 0.f, dp = 0.f;
#pragma unroll
    for (int j = 0; j < 4; j++) {
        float a = __bfloat162float(u1.h[j]);
        float b = __bfloat162float(u2.h[j]);
        sd1 += a * a; sd2 += b * b; dp += a * b;
    }
#pragma unroll
    for (int off = 32; off > 0; off >>= 1) {
        sd1 += __shfl_xor(sd1, off);
        sd2 += __shfl_xor(sd2, off);
        dp  += __shfl_xor(dp,  off);
    }
    if (lane == 0) {
        pos[p] = dp; pos[p + B_ROWS] = dp;
        selfdot[p] = sd1; selfdot[p + B_ROWS] = sd2;
    }
}

// ---------------------------------------------------------------------------
// Kernel 2 v6: wave-private staging, ZERO barriers, counted waitcnts.
//   Measured ranking (v0 43.8 < v3 47.2 < v4 51.0 < v2 61.0 < v5 62.6)
//   falsified occupancy/atomics/tile-size/LDS-removal; the remaining
//   candidate serializer is the per-tile 4-wave vmcnt(0)+lgkmcnt(0)+
//   s_barrier lockstep. v6 removes it: each wave stages its OWN 16 KB
//   buffer (single-buffered, validated gload_lds swizzle) and syncs only
//   with per-wave counted s_waitcnt:
//     loop top : vmcnt(2|0)  — own stage retired (2 mirror atomics may fly)
//     pre-stage: lgkmcnt(0)  — own ds_reads retired before overwrite
//   Stage for c+1 issues right after the kk loop; latency hides under the
//   epilogue. LDS = 4x16KB (~64.1KB) -> 2 blocks/CU, no cross-wave coupling.
// ---------------------------------------------------------------------------
__global__ __launch_bounds__(256, 2) void sim_rowsum_kernel(
    const short* __restrict__ z, float* __restrict__ rowsum,
    const float* __restrict__ pos, const float* __restrict__ selfdot,
    unsigned int* __restrict__ counter, float* __restrict__ out) {
    __shared__ __align__(16) short Bbuf[4][8192];   // 16 KB per wave, 1 buf
    __shared__ unsigned int done_s;
    __shared__ float sdata[4];

    const int tid  = threadIdx.x;
    const int lane = tid & 63;
    const int w    = tid >> 6;
    const int lm   = lane & 15;
    const int lg   = lane >> 4;
    const int fxor = lm & 7;

    const int s   = blockIdx.x >> 5;    // strip-pair 0..15
    const int q   = blockIdx.x & 31;    // segment 0..31
    const int L0  = 256 - 8 * s;        // tiles in first strip (panel s)
    const int cb  = (q * TT) >> 5;
    const int ce  = ((q + 1) * TT) >> 5;

    bf16x8 a[8][4];                     // A panel: 64 rows x 256 K (128 regs)
    floatx4 acc[4][2];
    float rsacc[4][4];

#pragma unroll
    for (int mi = 0; mi < 4; mi++)
#pragma unroll
        for (int r = 0; r < 4; r++) rsacc[mi][r] = 0.f;

    // ---- decode tile c -> (panel, colbase, mirror) ----
    auto decode = [&](int c, int& panel, int& colbase, bool& mirror) {
        int cloc;
        if (c < L0) { panel = s;      cloc = c; }
        else        { panel = 31 - s; cloc = c - L0; }
        colbase = panel * 256 + cloc * 32;
        mirror  = (cloc >= 8);
    };

    auto decodeCol = [&](int c) {
        int cloc, panel;
        if (c < L0) { panel = s;      cloc = c; }
        else        { panel = 31 - s; cloc = c - L0; }
        return panel * 256 + cloc * 32;
    };

    auto loadA = [&](int panel) {
#pragma unroll
        for (int kk = 0; kk < 8; kk++)
#pragma unroll
            for (int mi = 0; mi < 4; mi++)
                a[kk][mi] = *(const bf16x8*)(
                    z + (size_t)(panel * 256 + w * 64 + mi * 16 + lm) * D +
                    kk * 32 + lg * 8);
    };

    auto flushRs = [&](int panel) {
#pragma unroll
        for (int mi = 0; mi < 4; mi++)
#pragma unroll
            for (int r = 0; r < 4; r++) {
                float v = rsacc[mi][r];
                v += __shfl_xor(v, 1); v += __shfl_xor(v, 2);
                v += __shfl_xor(v, 4); v += __shfl_xor(v, 8);
                if (lm == 0)
                    atomicAdd(&rowsum[panel * 256 + w * 64 + mi * 16 + lg * 4 + r], v);
                rsacc[mi][r] = 0.f;
            }
    };

    // wave-private stage: 16 x (64 lanes x 16B) = 16 KB into Bbuf[w].
    // LDS dest linear (unit = j*64 + lane), source pre-swizzled so unit
    // col*32 + (c16 ^ (col&7)) holds data[col][c16]  (validated layout).
    auto stage = [&](int colbase) {
#pragma unroll
        for (int j = 0; j < 16; j++) {
            int col = j * 2 + (lane >> 5);
            int c16 = (lane & 31) ^ (col & 7);
            const short* src = z + (size_t)(colbase + col) * D + c16 * 8;
            __builtin_amdgcn_global_load_lds(
                (const __attribute__((address_space(1))) unsigned int*)src,
                (__attribute__((address_space(3))) unsigned int*)
                    &Bbuf[w][j * 512],
                16, 0, 0);
        }
    };

    // ---- prologue: stage first tile, load A panel (no barrier ever) ----
    int panel, colbase; bool mirror;
    decode(cb, panel, colbase, mirror);
    int curpanel = panel;
    stage(colbase);
    loadA(panel);
    bool pm = false;   // did previous tile trail 2 atomics after its stage?

    for (int c = cb; c < ce; c++) {
        decode(c, panel, colbase, mirror);

        // own stage retired? (2 newest mirror atomics may stay in flight)
        if (pm) asm volatile("s_waitcnt vmcnt(2)" ::: "memory");
        else    asm volatile("s_waitcnt vmcnt(0)" ::: "memory");

        if (panel != curpanel) {          // strip change (<=1 per block)
            flushRs(curpanel);
            loadA(panel);
            curpanel = panel;
        }

#pragma unroll
        for (int mi = 0; mi < 4; mi++)
#pragma unroll
            for (int ni = 0; ni < 2; ni++)
                acc[mi][ni] = (floatx4){0.f, 0.f, 0.f, 0.f};

#pragma unroll
        for (int kk = 0; kk < 8; kk++) {
            bf16x8 b0 = *(const bf16x8*)(
                &Bbuf[w][(((lm) * 32) + ((kk * 4 + lg) ^ fxor)) * 8]);
            bf16x8 b1 = *(const bf16x8*)(
                &Bbuf[w][(((16 + lm) * 32) + ((kk * 4 + lg) ^ fxor)) * 8]);
#pragma unroll
            for (int mi = 0; mi < 4; mi++)
                acc[mi][0] = __builtin_amdgcn_mfma_f32_16x16x32_bf16(
                    a[kk][mi], b0, acc[mi][0], 0, 0, 0);
#pragma unroll
            for (int mi = 0; mi < 4; mi++)
                acc[mi][1] = __builtin_amdgcn_mfma_f32_16x16x32_bf16(
                    a[kk][mi], b1, acc[mi][1], 0, 0, 0);
        }

        // own ds_reads retired -> safe to overwrite private buffer
        asm volatile("s_waitcnt lgkmcnt(0)" ::: "memory");
        if (c + 1 < ce)
            stage(decodeCol(c + 1));      // latency hides under epilogue

        // epilogue: exp(2*sim) -> register row-sums (+ mirror col-sums)
        float cs0 = 0.f, cs1 = 0.f;
#pragma unroll
        for (int mi = 0; mi < 4; mi++)
#pragma unroll
            for (int r = 0; r < 4; r++) {
                float e0 = __expf(2.0f * acc[mi][0][r]);
                float e1 = __expf(2.0f * acc[mi][1][r]);
                rsacc[mi][r] += e0 + e1;
                cs0 += e0; cs1 += e1;
            }
        if (mirror) {
            cs0 += __shfl_xor(cs0, 16); cs0 += __shfl_xor(cs0, 32);
            cs1 += __shfl_xor(cs1, 16); cs1 += __shfl_xor(cs1, 32);
            if (lane < 16) {
                atomicAdd(&rowsum[colbase + lane],      cs0);
                atomicAdd(&rowsum[colbase + 16 + lane], cs1);
            }
        }
        pm = mirror;
    }
    flushRs(curpanel);

    // ---- last-block-done: final loss ----
    __syncthreads();
    if (tid == 0) {
        __threadfence();
        done_s = atomicAdd(counter, 1u);
    }
    __syncthreads();
    if (done_s == (unsigned int)(NBLK2 - 1)) {
        __threadfence();
        float acc_l = 0.f;
#pragma unroll 4
        for (int r = tid; r < NROWS; r += 256) {
            float rsv = __hip_atomic_load(&rowsum[r], __ATOMIC_RELAXED,
                                          __HIP_MEMORY_SCOPE_AGENT);
            float denom = rsv - __expf(2.0f * selfdot[r]);
            acc_l += -2.0f * pos[r] + logf(denom);
        }
#pragma unroll
        for (int off = 32; off > 0; off >>= 1) acc_l += __shfl_xor(acc_l, off);
        if (lane == 0) sdata[w] = acc_l;
        __syncthreads();
        if (tid == 0)
            out[0] = (sdata[0] + sdata[1] + sdata[2] + sdata[3]) / (float)NROWS;
    }
}

// ---------------------------------------------------------------------------
extern "C" void kernel_launch(void* const* d_in, const int* in_sizes, int n_in,
                              void* d_out, int out_size, void* d_ws, size_t ws_size,
                              hipStream_t stream) {
    const float* xi = (const float*)d_in[0];
    const float* xj = (const float*)d_in[1];
    float* out      = (float*)d_out;

    char* ws        = (char*)d_ws;
    short* z        = (short*)ws;                             // 4 MiB
    float* rowsum   = (float*)(ws + (size_t)NROWS * D * 2);   // 32 KiB
    float* pos      = rowsum + NROWS;                         // 32 KiB
    float* selfdot  = pos + NROWS;                            // 32 KiB
    unsigned int* counter = (unsigned int*)(selfdot + NROWS);

    norm_pos_kernel<<<B_ROWS / 4, 256, 0, stream>>>(xi, xj, z, pos, selfdot,
                                                    rowsum, out, counter);
    sim_rowsum_kernel<<<NBLK2, 256, 0, stream>>>(z, rowsum, pos, selfdot,
                                                 counter, out);
}